// Round 8
// baseline (20.768 us; speedup 1.0000x reference)
//
#include <hip/hip_runtime.h>

// Rasterize_52321291600271 — round 8 (all-resident, one wave per tile)
// B=4, NV=1024, NF=1024, RASTER S=256, output 4x128x128 float32.
//
// 1024 blocks x 256 threads. Block g stages batch b=g>>8's vertices (8KB)
// into LDS once; its 4 waves each own tile t=4g+wid (8x8 subpixels) and
// scan the 16 64-face chunks independently:
//   - per-lane face-index load (next chunk prefetched in registers)
//   - LDS vertex gather + in-lane edge vectors (bit-exact IEEE f32 subs)
//   - conservative SAT cull (bbox + center+radius edge extrema,
//     MARGIN 1e-4 >> ~1e-6 FP error)
//   - ballot; per set bit, broadcast the 12 face floats from the owning
//     lane via readlane; exact 6-cross test (__fmul_rn/__fsub_rn, no FMA
//     — byte-identical to the passing round-7 kernel)
//   - wave-level early exit when all 64 subpixels covered
// No atomics, no inter-wave coordination, no barrier after staging.
// Epilogue per wave: vertical flip + 2x2 mean via intra-wave shuffles.

constexpr int S     = 256;
constexpr int NVERT = 1024;
constexpr int NFACE = 1024;
constexpr int OUTSZ = 128;

__global__ __launch_bounds__(256)
void raster_wpt(const float* __restrict__ verts,
                const int*   __restrict__ faces,
                float*       __restrict__ out)
{
    __shared__ float2 vlds[NVERT];                 // 8 KB vertex copy

    const int tid  = threadIdx.x;
    const int lane = tid & 63;
    const int wid  = tid >> 6;
    const int t    = (int)blockIdx.x * 4 + wid;    // global tile id
    const int b    = t >> 10;                      // 1024 tiles per image
    const int tt   = t & 1023;
    const int bx   = (tt & 31) << 3;               // tile origin (subpixels)
    const int by   = (tt >> 5) << 3;
    const int tx   = lane & 7;
    const int ty   = lane >> 3;
    const int sx   = bx + tx;
    const int sy   = by + ty;

    // (2j+1-S)/S exactly representable
    const float px  = (float)(2 * sx + 1 - S)       * (1.0f / (float)S);
    const float py  = (float)(2 * sy + 1 - S)       * (1.0f / (float)S);
    const float rx0 = (float)(2 * bx + 1 - S)       * (1.0f / (float)S);
    const float rx1 = (float)(2 * (bx + 7) + 1 - S) * (1.0f / (float)S);
    const float ry0 = (float)(2 * by + 1 - S)       * (1.0f / (float)S);
    const float ry1 = (float)(2 * (by + 7) + 1 - S) * (1.0f / (float)S);
    constexpr float MARGIN = 1e-4f;
    const float cx = (rx0 + rx1) * 0.5f;
    const float cy = (ry0 + ry1) * 0.5f;
    const float h  = (rx1 - rx0) * 0.5f;
    const float rx0m = rx0 - MARGIN, rx1m = rx1 + MARGIN;
    const float ry0m = ry0 - MARGIN, ry1m = ry1 + MARGIN;

    // ---- stage batch vertices into LDS (bit-exact copy) ----
    {
        const float4* __restrict__ v4 = (const float4*)(verts + (size_t)b * NVERT * 2);
        float4* __restrict__ l4 = (float4*)vlds;
        l4[tid]       = v4[tid];                   // 512 float4 total
        l4[tid + 256] = v4[tid + 256];
    }
    __syncthreads();

    const int* __restrict__ fb = faces + (size_t)b * NFACE * 3;

    bool covered = false;

    int i0 = fb[3 * lane + 0];                     // prime chunk 0
    int i1 = fb[3 * lane + 1];
    int i2 = fb[3 * lane + 2];

    for (int c0 = 0; c0 < NFACE; c0 += 64) {
        // ---- prefetch next chunk's indices ----
        const int nc = c0 + 64;
        int n0 = 0, n1 = 0, n2 = 0;
        if (nc < NFACE) {
            n0 = fb[3 * (nc + lane) + 0];
            n1 = fb[3 * (nc + lane) + 1];
            n2 = fb[3 * (nc + lane) + 2];
        }

        // ---- LDS vertex gather + in-lane edge vectors ----
        const float2 va = vlds[i0], vbb = vlds[i1], vcc = vlds[i2];
        const float xa = va.x,  ya = va.y;
        const float xb = vbb.x, yb = vbb.y;
        const float xc = vcc.x, yc = vcc.y;
        const float exab = __fsub_rn(xb, xa), eyab = __fsub_rn(yb, ya);
        const float exbc = __fsub_rn(xc, xb), eybc = __fsub_rn(yc, yb);
        const float exca = __fsub_rn(xa, xc), eyca = __fsub_rn(ya, yc);

        // ---- conservative SAT cull ----
        bool keep;
        {
            const float xmn = fminf(xa, fminf(xb, xc));
            const float xmx = fmaxf(xa, fmaxf(xb, xc));
            const float ymn = fminf(ya, fminf(yb, yc));
            const float ymx = fmaxf(ya, fmaxf(yb, yc));
            const bool bbok = (xmn <= rx1m) & (xmx >= rx0m) &
                              (ymn <= ry1m) & (ymx >= ry0m);
            #define EDGE_CR(ex, ey, vx, vy, Fc, rr)                           \
                const float Fc = (ex) * (cy - (vy)) - (ey) * (cx - (vx));     \
                const float rr = (fabsf(ex) + fabsf(ey)) * h;
            EDGE_CR(exab, eyab, xa, ya, FcAB, rAB)
            EDGE_CR(exbc, eybc, xb, yb, FcBC, rBC)
            EDGE_CR(exca, eyca, xc, yc, FcCA, rCA)
            #undef EDGE_CR
            const bool fwdP = (FcAB + rAB > -MARGIN) & (FcBC + rBC > -MARGIN) &
                              (FcCA + rCA > -MARGIN);
            const bool revP = (FcAB - rAB <  MARGIN) & (FcBC - rBC <  MARGIN) &
                              (FcCA - rCA <  MARGIN);
            keep = bbok & (fwdP | revP);
        }

        // ---- iterate survivors: register broadcast via readlane ----
        unsigned long long m = __ballot((int)keep);
        int nt = 0;
        #define RL(v) __int_as_float(__builtin_amdgcn_readlane(__float_as_int(v), f))
        while (m) {
            const int f = __ffsll(m) - 1;
            m &= m - 1;
            const float Xa = RL(xa), Ya = RL(ya);
            const float Xb = RL(xb), Yb = RL(yb);
            const float Xc = RL(xc), Yc = RL(yc);
            const float E0x = RL(exab), E0y = RL(eyab);
            const float E1x = RL(exbc), E1y = RL(eybc);
            const float E2x = RL(exca), E2y = RL(eyca);
            const float dxa = __fsub_rn(px, Xa), dya = __fsub_rn(py, Ya);
            const float dxb = __fsub_rn(px, Xb), dyb = __fsub_rn(py, Yb);
            const float dxc = __fsub_rn(px, Xc), dyc = __fsub_rn(py, Yc);
            const float F0 = __fsub_rn(__fmul_rn(E0x, dya), __fmul_rn(E0y, dxa));
            const float F1 = __fsub_rn(__fmul_rn(E1x, dyb), __fmul_rn(E1y, dxb));
            const float F2 = __fsub_rn(__fmul_rn(E2x, dyc), __fmul_rn(E2y, dxc));
            const float R0 = __fsub_rn(__fmul_rn(E1y, dxc), __fmul_rn(E1x, dyc));
            const float R1 = __fsub_rn(__fmul_rn(E0y, dxb), __fmul_rn(E0x, dyb));
            const float R2 = __fsub_rn(__fmul_rn(E2y, dxa), __fmul_rn(E2x, dya));
            const bool fwd = (F0 > 0.0f) & (F1 > 0.0f) & (F2 > 0.0f);
            const bool rev = (R0 > 0.0f) & (R1 > 0.0f) & (R2 > 0.0f);
            covered = covered || fwd || rev;
            if (((++nt) & 3) == 0 && __all((int)covered)) break;
        }
        #undef RL

        if (__all((int)covered)) break;            // wave-level early exit
        i0 = n0; i1 = n1; i2 = n2;
    }

    // ---- epilogue: vertical flip + 2x2 mean (per wave, no barrier) ----
    float c = covered ? 1.0f : 0.0f;
    c += __shfl_xor(c, 1);                         // tx neighbor
    c += __shfl_xor(c, 8);                         // ty neighbor
    if (((lane & 1) == 0) && ((lane & 8) == 0)) {
        const int X = sx >> 1;
        const int Y = (OUTSZ - 1) - (sy >> 1);     // vertical flip
        out[((size_t)b * OUTSZ + Y) * OUTSZ + X] = c * 0.25f;
    }
}

extern "C" void kernel_launch(void* const* d_in, const int* in_sizes, int n_in,
                              void* d_out, int out_size, void* d_ws, size_t ws_size,
                              hipStream_t stream) {
    const float* verts = (const float*)d_in[0];
    const int*   faces = (const int*)d_in[1];
    float*       out   = (float*)d_out;

    const int B = in_sizes[0] / (NVERT * 2);       // = 4
    const int nTiles = B * (S / 8) * (S / 8);      // 4096
    raster_wpt<<<dim3(nTiles / 4), dim3(256), 0, stream>>>(verts, faces, out);
}

// Round 9
// 20.253 us; speedup vs baseline: 1.0254x; 1.0254x over previous
//
#include <hip/hip_runtime.h>

// Rasterize_52321291600271 — round 9 (r7 structure + full-inside fast path)
// B=4, NV=1024, NF=1024, RASTER S=256, output 4x128x128 float32.
//
// One 256-thread block per 8x8-subpixel tile; 4 waves map their 64 lanes
// to the SAME 64 subpixels; wave w scans chunks {w, w+4, w+8, w+12}.
// Per 64-face chunk (no __syncthreads in the loop):
//   - per-lane face-index load (next chunk prefetched in registers)
//   - vertex gather from an 8KB LDS copy; in-lane edge vectors
//   - conservative SAT cull (bbox + center+radius edge extrema)
//   - NEW: full-inside test — if any lane's face has min-cross > MARGIN
//     (fwd) or max-cross < -MARGIN (rev) over the whole tile rect, every
//     subpixel center is strictly inside -> wave covered, no exact tests.
//     (MARGIN 1e-4 >> ~5e-6 FP error bound; rev crosses are exact IEEE
//     negations of fwd, so max-F < 0 <=> all rev crosses > 0.)
//   - else: ballot survivors; readlane-broadcast exact 6-cross test
//     (__fmul_rn/__fsub_rn, no FMA — byte-identical to passing r7/r8)
//   - coverage union across waves via 64-bit LDS atomicOr; all waves
//     early-exit when the union is full (monotone, barrier-free)
// Epilogue: union mask -> vertical flip + 2x2 mean, written by wave 0.

constexpr int S     = 256;
constexpr int NVERT = 1024;
constexpr int NFACE = 1024;
constexpr int OUTSZ = 128;

__global__ __launch_bounds__(256)
void raster_fused(const float* __restrict__ verts,
                  const int*   __restrict__ faces,
                  float*       __restrict__ out)
{
    __shared__ float2 vlds[NVERT];                 // 8 KB vertex copy
    __shared__ unsigned long long covMask;         // coverage union

    const int b    = blockIdx.z;
    const int tid  = threadIdx.x;
    const int lane = tid & 63;
    const int wid  = tid >> 6;
    const int tx   = lane & 7;
    const int ty   = lane >> 3;
    const int bx   = (int)(blockIdx.x << 3);       // signed tile origin
    const int by   = (int)(blockIdx.y << 3);
    const int sx   = bx + tx;
    const int sy   = by + ty;

    // (2j+1-S)/S exactly representable
    const float px  = (float)(2 * sx + 1 - S)       * (1.0f / (float)S);
    const float py  = (float)(2 * sy + 1 - S)       * (1.0f / (float)S);
    const float rx0 = (float)(2 * bx + 1 - S)       * (1.0f / (float)S);
    const float rx1 = (float)(2 * (bx + 7) + 1 - S) * (1.0f / (float)S);
    const float ry0 = (float)(2 * by + 1 - S)       * (1.0f / (float)S);
    const float ry1 = (float)(2 * (by + 7) + 1 - S) * (1.0f / (float)S);
    constexpr float MARGIN = 1e-4f;
    const float cx = (rx0 + rx1) * 0.5f;
    const float cy = (ry0 + ry1) * 0.5f;
    const float h  = (rx1 - rx0) * 0.5f;
    const float rx0m = rx0 - MARGIN, rx1m = rx1 + MARGIN;
    const float ry0m = ry0 - MARGIN, ry1m = ry1 + MARGIN;

    // ---- stage batch vertices into LDS (bit-exact copy), init mask ----
    {
        const float4* __restrict__ v4 = (const float4*)(verts + (size_t)b * NVERT * 2);
        float4* __restrict__ l4 = (float4*)vlds;
        l4[tid]       = v4[tid];                   // 512 float4 total
        l4[tid + 256] = v4[tid + 256];
    }
    if (tid == 0) covMask = 0ull;
    __syncthreads();

    const int* __restrict__ fb = faces + (size_t)b * NFACE * 3;

    bool covered = false;

    int c0 = wid * 64;
    int i0 = fb[3 * (c0 + lane) + 0];
    int i1 = fb[3 * (c0 + lane) + 1];
    int i2 = fb[3 * (c0 + lane) + 2];

    for (; c0 < NFACE; c0 += 256) {
        // ---- prefetch next chunk's indices (wave-uniform guard) ----
        const int nc = c0 + 256;
        int n0 = 0, n1 = 0, n2 = 0;
        if (nc < NFACE) {
            n0 = fb[3 * (nc + lane) + 0];
            n1 = fb[3 * (nc + lane) + 1];
            n2 = fb[3 * (nc + lane) + 2];
        }

        // ---- LDS vertex gather + in-lane edge vectors ----
        const float2 va = vlds[i0], vbb = vlds[i1], vcc = vlds[i2];
        const float xa = va.x,  ya = va.y;
        const float xb = vbb.x, yb = vbb.y;
        const float xc = vcc.x, yc = vcc.y;
        const float exab = __fsub_rn(xb, xa), eyab = __fsub_rn(yb, ya);
        const float exbc = __fsub_rn(xc, xb), eybc = __fsub_rn(yc, yb);
        const float exca = __fsub_rn(xa, xc), eyca = __fsub_rn(ya, yc);

        // ---- conservative SAT cull + full-inside test ----
        bool keep, fullIn;
        {
            const float xmn = fminf(xa, fminf(xb, xc));
            const float xmx = fmaxf(xa, fmaxf(xb, xc));
            const float ymn = fminf(ya, fminf(yb, yc));
            const float ymx = fmaxf(ya, fmaxf(yb, yc));
            const bool bbok = (xmn <= rx1m) & (xmx >= rx0m) &
                              (ymn <= ry1m) & (ymx >= ry0m);
            #define EDGE_CR(ex, ey, vx, vy, Fc, rr)                           \
                const float Fc = (ex) * (cy - (vy)) - (ey) * (cx - (vx));     \
                const float rr = (fabsf(ex) + fabsf(ey)) * h;
            EDGE_CR(exab, eyab, xa, ya, FcAB, rAB)
            EDGE_CR(exbc, eybc, xb, yb, FcBC, rBC)
            EDGE_CR(exca, eyca, xc, yc, FcCA, rCA)
            #undef EDGE_CR
            const bool fwdP = (FcAB + rAB > -MARGIN) & (FcBC + rBC > -MARGIN) &
                              (FcCA + rCA > -MARGIN);
            const bool revP = (FcAB - rAB <  MARGIN) & (FcBC - rBC <  MARGIN) &
                              (FcCA - rCA <  MARGIN);
            keep = bbok & (fwdP | revP);
            // strict containment of the whole rect (conservative-safe):
            const bool fullF = (FcAB - rAB >  MARGIN) & (FcBC - rBC >  MARGIN) &
                               (FcCA - rCA >  MARGIN);
            const bool fullR = (FcAB + rAB < -MARGIN) & (FcBC + rBC < -MARGIN) &
                               (FcCA + rCA < -MARGIN);
            fullIn = fullF | fullR;
        }

        if (__any((int)fullIn)) {
            covered = true;                        // whole tile strictly inside
        } else {
            // ---- iterate survivors: register broadcast via readlane ----
            unsigned long long m = __ballot((int)keep);
            int nt = 0;
            #define RL(v) __int_as_float(__builtin_amdgcn_readlane(__float_as_int(v), f))
            while (m) {
                const int f = __ffsll(m) - 1;
                m &= m - 1;
                const float Xa = RL(xa), Ya = RL(ya);
                const float Xb = RL(xb), Yb = RL(yb);
                const float Xc = RL(xc), Yc = RL(yc);
                const float E0x = RL(exab), E0y = RL(eyab);
                const float E1x = RL(exbc), E1y = RL(eybc);
                const float E2x = RL(exca), E2y = RL(eyca);
                const float dxa = __fsub_rn(px, Xa), dya = __fsub_rn(py, Ya);
                const float dxb = __fsub_rn(px, Xb), dyb = __fsub_rn(py, Yb);
                const float dxc = __fsub_rn(px, Xc), dyc = __fsub_rn(py, Yc);
                const float F0 = __fsub_rn(__fmul_rn(E0x, dya), __fmul_rn(E0y, dxa));
                const float F1 = __fsub_rn(__fmul_rn(E1x, dyb), __fmul_rn(E1y, dxb));
                const float F2 = __fsub_rn(__fmul_rn(E2x, dyc), __fmul_rn(E2y, dxc));
                const float R0 = __fsub_rn(__fmul_rn(E1y, dxc), __fmul_rn(E1x, dyc));
                const float R1 = __fsub_rn(__fmul_rn(E0y, dxb), __fmul_rn(E0x, dyb));
                const float R2 = __fsub_rn(__fmul_rn(E2y, dxa), __fmul_rn(E2x, dya));
                const bool fwd = (F0 > 0.0f) & (F1 > 0.0f) & (F2 > 0.0f);
                const bool rev = (R0 > 0.0f) & (R1 > 0.0f) & (R2 > 0.0f);
                covered = covered || fwd || rev;
                if (((++nt) & 3) == 0 && __all((int)covered)) break;
            }
            #undef RL
        }

        // ---- merge this wave's coverage into the block union ----
        const unsigned long long m2 = __ballot((int)covered);
        unsigned long long u = 0ull;
        if (lane == 0) u = atomicOr(&covMask, m2) | m2;
        u = __shfl(u, 0);
        if (u == ~0ull) break;                      // union full: all waves exit

        i0 = n0; i1 = n1; i2 = n2;
    }

    __syncthreads();                                // all waves contributed

    // ---- epilogue: union mask -> flip + 2x2 mean (wave 0 only) ----
    if (tid < 64) {
        const unsigned long long u = covMask;
        if (((tx & 1) == 0) && ((ty & 1) == 0)) {
            const float c = (float)(((u >> lane) & 1ull) +
                                    ((u >> (lane ^ 1)) & 1ull) +
                                    ((u >> (lane ^ 8)) & 1ull) +
                                    ((u >> (lane ^ 9)) & 1ull));
            const int X = sx >> 1;
            const int Y = (OUTSZ - 1) - (sy >> 1);  // vertical flip
            out[((size_t)b * OUTSZ + Y) * OUTSZ + X] = c * 0.25f;
        }
    }
}

extern "C" void kernel_launch(void* const* d_in, const int* in_sizes, int n_in,
                              void* d_out, int out_size, void* d_ws, size_t ws_size,
                              hipStream_t stream) {
    const float* verts = (const float*)d_in[0];
    const int*   faces = (const int*)d_in[1];
    float*       out   = (float*)d_out;

    const int B = in_sizes[0] / (NVERT * 2);        // = 4
    dim3 grid(S / 8, S / 8, B);
    raster_fused<<<grid, dim3(256), 0, stream>>>(verts, faces, out);
}

// Round 10
// 19.528 us; speedup vs baseline: 1.0635x; 1.0371x over previous
//
#include <hip/hip_runtime.h>

// Rasterize_52321291600271 — round 10 (final: resubmit best variant, r7)
// B=4, NV=1024, NF=1024, RASTER S=256, output 4x128x128 float32.
//
// One 256-thread block per 8x8-subpixel tile; 4 waves map their 64 lanes
// to the SAME 64 subpixels; wave w scans chunks {w, w+4, w+8, w+12}.
// Per 64-face chunk (no __syncthreads in the loop):
//   - per-lane face-index load (next chunk prefetched in registers)
//   - vertex gather from an 8KB LDS copy; in-lane edge vectors (bit-exact
//     IEEE f32 subs, as the reference)
//   - conservative SAT cull (bbox + center+radius edge extrema,
//     MARGIN 1e-4 >> ~1e-6 FP error)
//   - ballot; for each set bit f: broadcast the 12 face floats from lane f
//     via __builtin_amdgcn_readlane (register->scalar, no memory), run the
//     exact 6-cross test (__fmul_rn/__fsub_rn, no FMA — byte-identical to
//     the reference's numpy/f32 semantics); check __all(covered) every 4
//   - coverage union across waves via 64-bit LDS atomicOr; all waves
//     early-exit when the union is full (monotone, barrier-free)
// Epilogue: union mask -> vertical flip + 2x2 mean, written by wave 0.
//
// Session evidence (r6-r9): dur_us flat at 19.5-20.8 across 4 structurally
// different kernels with >4x modeled-work differences -> harness launch/
// graph floor dominates; this variant measured best (19.5 us).

constexpr int S     = 256;
constexpr int NVERT = 1024;
constexpr int NFACE = 1024;
constexpr int OUTSZ = 128;

__global__ __launch_bounds__(256)
void raster_fused(const float* __restrict__ verts,
                  const int*   __restrict__ faces,
                  float*       __restrict__ out)
{
    __shared__ float2 vlds[NVERT];                 // 8 KB vertex copy
    __shared__ unsigned long long covMask;         // coverage union

    const int b    = blockIdx.z;
    const int tid  = threadIdx.x;
    const int lane = tid & 63;
    const int wid  = tid >> 6;
    const int tx   = lane & 7;
    const int ty   = lane >> 3;
    const int bx   = (int)(blockIdx.x << 3);       // signed tile origin
    const int by   = (int)(blockIdx.y << 3);
    const int sx   = bx + tx;
    const int sy   = by + ty;

    // (2j+1-S)/S exactly representable
    const float px  = (float)(2 * sx + 1 - S)       * (1.0f / (float)S);
    const float py  = (float)(2 * sy + 1 - S)       * (1.0f / (float)S);
    const float rx0 = (float)(2 * bx + 1 - S)       * (1.0f / (float)S);
    const float rx1 = (float)(2 * (bx + 7) + 1 - S) * (1.0f / (float)S);
    const float ry0 = (float)(2 * by + 1 - S)       * (1.0f / (float)S);
    const float ry1 = (float)(2 * (by + 7) + 1 - S) * (1.0f / (float)S);
    constexpr float MARGIN = 1e-4f;
    const float cx = (rx0 + rx1) * 0.5f;
    const float cy = (ry0 + ry1) * 0.5f;
    const float h  = (rx1 - rx0) * 0.5f;
    const float rx0m = rx0 - MARGIN, rx1m = rx1 + MARGIN;
    const float ry0m = ry0 - MARGIN, ry1m = ry1 + MARGIN;

    // ---- stage batch vertices into LDS (bit-exact copy), init mask ----
    {
        const float4* __restrict__ v4 = (const float4*)(verts + (size_t)b * NVERT * 2);
        float4* __restrict__ l4 = (float4*)vlds;
        l4[tid]       = v4[tid];                   // 512 float4 total
        l4[tid + 256] = v4[tid + 256];
    }
    if (tid == 0) covMask = 0ull;
    __syncthreads();

    const int* __restrict__ fb = faces + (size_t)b * NFACE * 3;

    bool covered = false;

    int c0 = wid * 64;
    int i0 = fb[3 * (c0 + lane) + 0];
    int i1 = fb[3 * (c0 + lane) + 1];
    int i2 = fb[3 * (c0 + lane) + 2];

    for (; c0 < NFACE; c0 += 256) {
        // ---- prefetch next chunk's indices (wave-uniform guard) ----
        const int nc = c0 + 256;
        int n0 = 0, n1 = 0, n2 = 0;
        if (nc < NFACE) {
            n0 = fb[3 * (nc + lane) + 0];
            n1 = fb[3 * (nc + lane) + 1];
            n2 = fb[3 * (nc + lane) + 2];
        }

        // ---- LDS vertex gather + in-lane edge vectors ----
        const float2 va = vlds[i0], vbb = vlds[i1], vcc = vlds[i2];
        const float xa = va.x,  ya = va.y;
        const float xb = vbb.x, yb = vbb.y;
        const float xc = vcc.x, yc = vcc.y;
        const float exab = __fsub_rn(xb, xa), eyab = __fsub_rn(yb, ya);
        const float exbc = __fsub_rn(xc, xb), eybc = __fsub_rn(yc, yb);
        const float exca = __fsub_rn(xa, xc), eyca = __fsub_rn(ya, yc);

        // ---- conservative SAT cull ----
        bool keep;
        {
            const float xmn = fminf(xa, fminf(xb, xc));
            const float xmx = fmaxf(xa, fmaxf(xb, xc));
            const float ymn = fminf(ya, fminf(yb, yc));
            const float ymx = fmaxf(ya, fmaxf(yb, yc));
            const bool bbok = (xmn <= rx1m) & (xmx >= rx0m) &
                              (ymn <= ry1m) & (ymx >= ry0m);
            #define EDGE_CR(ex, ey, vx, vy, Fc, rr)                           \
                const float Fc = (ex) * (cy - (vy)) - (ey) * (cx - (vx));     \
                const float rr = (fabsf(ex) + fabsf(ey)) * h;
            EDGE_CR(exab, eyab, xa, ya, FcAB, rAB)
            EDGE_CR(exbc, eybc, xb, yb, FcBC, rBC)
            EDGE_CR(exca, eyca, xc, yc, FcCA, rCA)
            #undef EDGE_CR
            const bool fwdP = (FcAB + rAB > -MARGIN) & (FcBC + rBC > -MARGIN) &
                              (FcCA + rCA > -MARGIN);
            const bool revP = (FcAB - rAB <  MARGIN) & (FcBC - rBC <  MARGIN) &
                              (FcCA - rCA <  MARGIN);
            keep = bbok & (fwdP | revP);
        }

        // ---- iterate survivors: register broadcast via readlane ----
        unsigned long long m = __ballot((int)keep);
        int nt = 0;
        #define RL(v) __int_as_float(__builtin_amdgcn_readlane(__float_as_int(v), f))
        while (m) {
            const int f = __ffsll(m) - 1;
            m &= m - 1;
            const float Xa = RL(xa), Ya = RL(ya);
            const float Xb = RL(xb), Yb = RL(yb);
            const float Xc = RL(xc), Yc = RL(yc);
            const float E0x = RL(exab), E0y = RL(eyab);
            const float E1x = RL(exbc), E1y = RL(eybc);
            const float E2x = RL(exca), E2y = RL(eyca);
            const float dxa = __fsub_rn(px, Xa), dya = __fsub_rn(py, Ya);
            const float dxb = __fsub_rn(px, Xb), dyb = __fsub_rn(py, Yb);
            const float dxc = __fsub_rn(px, Xc), dyc = __fsub_rn(py, Yc);
            const float F0 = __fsub_rn(__fmul_rn(E0x, dya), __fmul_rn(E0y, dxa));
            const float F1 = __fsub_rn(__fmul_rn(E1x, dyb), __fmul_rn(E1y, dxb));
            const float F2 = __fsub_rn(__fmul_rn(E2x, dyc), __fmul_rn(E2y, dxc));
            const float R0 = __fsub_rn(__fmul_rn(E1y, dxc), __fmul_rn(E1x, dyc));
            const float R1 = __fsub_rn(__fmul_rn(E0y, dxb), __fmul_rn(E0x, dyb));
            const float R2 = __fsub_rn(__fmul_rn(E2y, dxa), __fmul_rn(E2x, dya));
            const bool fwd = (F0 > 0.0f) & (F1 > 0.0f) & (F2 > 0.0f);
            const bool rev = (R0 > 0.0f) & (R1 > 0.0f) & (R2 > 0.0f);
            covered = covered || fwd || rev;
            if (((++nt) & 3) == 0 && __all((int)covered)) break;
        }
        #undef RL

        // ---- merge this wave's coverage into the block union ----
        const unsigned long long m2 = __ballot((int)covered);
        unsigned long long u = 0ull;
        if (lane == 0) u = atomicOr(&covMask, m2) | m2;
        u = __shfl(u, 0);
        if (u == ~0ull) break;                      // union full: all waves exit

        i0 = n0; i1 = n1; i2 = n2;
    }

    __syncthreads();                                // all waves contributed

    // ---- epilogue: union mask -> flip + 2x2 mean (wave 0 only) ----
    if (tid < 64) {
        const unsigned long long u = covMask;
        if (((tx & 1) == 0) && ((ty & 1) == 0)) {
            const float c = (float)(((u >> lane) & 1ull) +
                                    ((u >> (lane ^ 1)) & 1ull) +
                                    ((u >> (lane ^ 8)) & 1ull) +
                                    ((u >> (lane ^ 9)) & 1ull));
            const int X = sx >> 1;
            const int Y = (OUTSZ - 1) - (sy >> 1);  // vertical flip
            out[((size_t)b * OUTSZ + Y) * OUTSZ + X] = c * 0.25f;
        }
    }
}

extern "C" void kernel_launch(void* const* d_in, const int* in_sizes, int n_in,
                              void* d_out, int out_size, void* d_ws, size_t ws_size,
                              hipStream_t stream) {
    const float* verts = (const float*)d_in[0];
    const int*   faces = (const int*)d_in[1];
    float*       out   = (float*)d_out;

    const int B = in_sizes[0] / (NVERT * 2);        // = 4
    dim3 grid(S / 8, S / 8, B);
    raster_fused<<<grid, dim3(256), 0, stream>>>(verts, faces, out);
}